// Round 4
// baseline (758.849 us; speedup 1.0000x reference)
//
#include <hip/hip_runtime.h>
#include <hip/hip_bf16.h>

using bf16 = __hip_bfloat16;
typedef __attribute__((ext_vector_type(8))) short short8;   // 8 bf16 = 4 VGPRs (MFMA A/B frag)
typedef __attribute__((ext_vector_type(4))) float f32x4;    // MFMA C/D frag

// async global->LDS, 16B per lane; LDS dest = wave-uniform base + lane*16
#define GLL16(gp, lp) __builtin_amdgcn_global_load_lds( \
    (__attribute__((address_space(1))) void*)(gp),      \
    (__attribute__((address_space(3))) void*)(lp), 16, 0, 0)

__device__ __forceinline__ float b2f(bf16 x) { return __bfloat162float(x); }
__device__ __forceinline__ bf16 f2b(float x) { return __float2bfloat16(x); }
__device__ __forceinline__ float s2f(short x) {
  unsigned u = ((unsigned)(unsigned short)x) << 16;
  return __uint_as_float(u);
}
__device__ __forceinline__ short f2s(float x) {
  bf16 h = __float2bfloat16(x);
  return *reinterpret_cast<short*>(&h);
}

#define TRIG_C (1.5707963268f / 2048.0f)   // (pi/2)/len, len = T = S = 2048

// ---------------------------------------------------------------------------
// dtype detector: bf16-pair words have bits[14:7] = bf16 exponent of the even
// element, concentrated in [118,134] for ~N(0,1) data (~99%). f32 words have
// uniform middle-mantissa bits there (~7%). flag=1 -> bf16, flag=0 -> f32.
// ---------------------------------------------------------------------------
__global__ void detect_dtype(const unsigned* __restrict__ q, int* __restrict__ flag)
{
  const int l = threadIdx.x;   // 64 threads
  int cnt = 0;
#pragma unroll
  for (int i = 0; i < 16; ++i) {
    const unsigned w = q[i * 64 + l];
    const unsigned e = (w >> 7) & 0xFFu;
    cnt += (e >= 118u && e <= 134u) ? 1 : 0;
  }
#pragma unroll
  for (int off = 32; off > 0; off >>= 1) cnt += __shfl_down(cnt, off);
  if (l == 0) *flag = (cnt > 512) ? 1 : 0;
}

// stages a 128x64 bf16 tile into LDS from either bf16 or f32 global memory.
// chunk c covers rows [c*8, c*8+8) x 64 cols; this thread's wave does c=w*4..w*4+3.
__device__ __forceinline__ void stage_tile(const void* G, long rowStride, long rowBase,
                                           int kt, bf16* lds, int isb, int w, int l)
{
  const int lrow = l >> 3, lcol = (l & 7) * 8;
  if (isb) {
    const bf16* Gb = (const bf16*)G;
#pragma unroll
    for (int i = 0; i < 4; ++i) {
      const int c = w * 4 + i, r = c * 8 + lrow;
      GLL16(Gb + (rowBase + r) * rowStride + kt + lcol, &lds[c * 512]);
    }
  } else {
    const float* Gf = (const float*)G;
#pragma unroll
    for (int i = 0; i < 4; ++i) {
      const int c = w * 4 + i, r = c * 8 + lrow;
      const float* p = Gf + (rowBase + r) * rowStride + kt + lcol;
      const f32x4 f0 = *(const f32x4*)p;
      const f32x4 f1 = *(const f32x4*)(p + 4);
      short8 o;
#pragma unroll
      for (int j = 0; j < 4; ++j) { o[j] = f2s(f0[j]); o[4 + j] = f2s(f1[j]); }
      *(short8*)&lds[c * 512 + l * 8] = o;
    }
  }
}

__device__ __forceinline__ float bload(const void* b, int i, int isb) {
  return isb ? b2f(((const bf16*)b)[i]) : ((const float*)b)[i];
}

// ---------------------------------------------------------------------------
// NT GEMM: A (M=16384,K=1024) row-major, W (N=1024,K=1024) row-major.
// 128x128 tile, BK=64, 256 thr (4 waves), each wave 64x64 = 4x4 mfma tiles.
// MODE 0: q-proj -> Qh  (bh, 2048, 64) d-contig, relu(v*0.125)   [out bf16]
// MODE 1: k-proj -> KhT (bh, 64, 2048) s-contig, relu(v)         [out bf16]
// MODE 2: v-proj -> VhT (bh, 64, 2048) s-contig                  [out bf16]
// MODE 3: o-proj -> out (16384, 1024)  row-major                 [out = flag dtype]
// A dtype: modes 0-2 = flag dtype (harness input); mode 3 = bf16 (internal ATT).
// ---------------------------------------------------------------------------
template<int MODE>
__global__ void proj_gemm(const void* __restrict__ A, const void* __restrict__ W,
                          const void* __restrict__ bias, void* __restrict__ O,
                          const int* __restrict__ flag)
{
  constexpr int K = 1024;
  constexpr int BK = 64;
  __shared__ __align__(16) bf16 As[128 * BK];
  __shared__ __align__(16) bf16 Bs[128 * BK];

  const int isb = flag[0];
  const int aIsB = (MODE == 3) ? 1 : isb;

  const int tid = threadIdx.x;
  const int w = tid >> 6, l = tid & 63;
  const int quad = l >> 4, l16 = l & 15;
  const long mblk = (long)blockIdx.y * 128;
  const int  nblk = blockIdx.x * 128;
  const int wr = (w >> 1) * 64, wc = (w & 1) * 64;

  f32x4 acc[4][4] = {};

  for (int kt = 0; kt < K; kt += BK) {
    stage_tile(A, K, mblk, kt, As, aIsB, w, l);
    stage_tile(W, K, nblk, kt, Bs, isb, w, l);
    __syncthreads();   // drains vmcnt + lgkmcnt -> LDS data landed
#pragma unroll
    for (int kk = 0; kk < BK; kk += 32) {
      const int ko = kk + quad * 8;
      short8 a[4], b[4];
#pragma unroll
      for (int u = 0; u < 4; ++u)
        a[u] = *(const short8*)&As[(wr + u * 16 + l16) * BK + ko];
#pragma unroll
      for (int u = 0; u < 4; ++u)
        b[u] = *(const short8*)&Bs[(wc + u * 16 + l16) * BK + ko];
#pragma unroll
      for (int tm = 0; tm < 4; ++tm)
#pragma unroll
        for (int tn = 0; tn < 4; ++tn)
          acc[tm][tn] = __builtin_amdgcn_mfma_f32_16x16x32_bf16(a[tm], b[tn], acc[tm][tn], 0, 0, 0);
    }
    __syncthreads();
  }

  // epilogue: C/D layout col=l&15, row=quad*4+reg
#pragma unroll
  for (int tm = 0; tm < 4; ++tm) {
    const int row0 = (int)mblk + wr + tm * 16 + quad * 4;
#pragma unroll
    for (int tn = 0; tn < 4; ++tn) {
      const int col = nblk + wc + tn * 16 + l16;
      const float bc = bload(bias, col, isb);
#pragma unroll
      for (int j = 0; j < 4; ++j) {
        const int row = row0 + j;
        float v = acc[tm][tn][j] + bc;
        if (MODE == 0) {
          const int t = row >> 3, bb = row & 7;           // row = t*8 + b
          const int h = col >> 6, d = col & 63;
          ((bf16*)O)[((long)(bb * 16 + h) * 2048 + t) * 64 + d] = f2b(fmaxf(v * 0.125f, 0.f));
        } else if (MODE == 1) {
          const int s = row >> 3, bb = row & 7;
          const int h = col >> 6, d = col & 63;
          ((bf16*)O)[((long)(bb * 16 + h) * 64 + d) * 2048 + s] = f2b(fmaxf(v, 0.f));
        } else if (MODE == 2) {
          const int s = row >> 3, bb = row & 7;
          const int h = col >> 6, e = col & 63;
          ((bf16*)O)[((long)(bb * 16 + h) * 64 + e) * 2048 + s] = f2b(v);
        } else {
          if (isb) ((bf16*)O)[(long)row * 1024 + col] = f2b(v);
          else     ((float*)O)[(long)row * 1024 + col] = v;
        }
      }
    }
  }
}

// ---------------------------------------------------------------------------
// ksum2[bh*128 + d]      = sum_s sin_s * KhT[bh][d][s]
// ksum2[bh*128 + 64 + d] = sum_s cos_s * KhT[bh][d][s]
// ---------------------------------------------------------------------------
__global__ void ksum2_kernel(const bf16* __restrict__ KhT, float* __restrict__ ksum2)
{
  const int gw = (blockIdx.x * 256 + threadIdx.x) >> 6;   // 0..8191
  const int l = threadIdx.x & 63;
  const int bh = gw >> 6, d = gw & 63;
  const bf16* row = KhT + ((long)bh * 64 + d) * 2048;
  float ss = 0.f, cc = 0.f;
#pragma unroll
  for (int i = 0; i < 4; ++i) {
    short8 v = *(const short8*)&row[i * 512 + l * 8];
#pragma unroll
    for (int j = 0; j < 8; ++j) {
      const int s = i * 512 + l * 8 + j;
      const float ang = (float)(s + 1) * TRIG_C;
      const float f = s2f(v[j]);
      ss += f * __sinf(ang);
      cc += f * __cosf(ang);
    }
  }
#pragma unroll
  for (int off = 32; off > 0; off >>= 1) {
    ss += __shfl_down(ss, off);
    cc += __shfl_down(cc, off);
  }
  if (l == 0) {
    ksum2[bh * 128 + d]      = ss;
    ksum2[bh * 128 + 64 + d] = cc;
  }
}

// ---------------------------------------------------------------------------
// kv2[bh][e'][d], e'<64: sum_s sin_s*v[s,e]*k[s,d]; e'>=64: cos version.
// M=128 (e'), N=64 (d), K=2048. One block per bh.
// ---------------------------------------------------------------------------
__global__ void kv_gemm(const bf16* __restrict__ VhT, const bf16* __restrict__ KhT,
                        bf16* __restrict__ kv2)
{
  __shared__ __align__(16) bf16 As[128 * 64];
  __shared__ __align__(16) bf16 Bs[64 * 64];
  const int bh = blockIdx.x;
  const int tid = threadIdx.x, w = tid >> 6, l = tid & 63;
  const int quad = l >> 4, l16 = l & 15;
  const int lrow = l >> 3, lcol = (l & 7) * 8;
  const bf16* Vg = VhT + (long)bh * 64 * 2048;
  const bf16* Kg = KhT + (long)bh * 64 * 2048;
  const int ar = tid >> 2, ac = (tid & 3) * 16;   // A-staging role

  f32x4 acc[2][4] = {};

  for (int kt = 0; kt < 2048; kt += 64) {
#pragma unroll
    for (int i = 0; i < 2; ++i) {                 // Bs: KhT rows d=0..63
      const int c = w * 2 + i, r = c * 8 + lrow;
      GLL16(Kg + (long)r * 2048 + kt + lcol, &Bs[c * 512]);
    }
    // As: load V tile 64x64, scale by sin/cos, write expanded 128x64
    short8 v0 = *(const short8*)&Vg[(long)ar * 2048 + kt + ac];
    short8 v1 = *(const short8*)&Vg[(long)ar * 2048 + kt + ac + 8];
    short8 s0, s1, c0, c1;
#pragma unroll
    for (int j = 0; j < 8; ++j) {
      const int sA = kt + ac + j, sB = sA + 8;
      const float angA = (float)(sA + 1) * TRIG_C, angB = (float)(sB + 1) * TRIG_C;
      const float fA = s2f(v0[j]), fB = s2f(v1[j]);
      s0[j] = f2s(fA * __sinf(angA)); c0[j] = f2s(fA * __cosf(angA));
      s1[j] = f2s(fB * __sinf(angB)); c1[j] = f2s(fB * __cosf(angB));
    }
    *(short8*)&As[ar * 64 + ac]            = s0;
    *(short8*)&As[ar * 64 + ac + 8]        = s1;
    *(short8*)&As[(ar + 64) * 64 + ac]     = c0;
    *(short8*)&As[(ar + 64) * 64 + ac + 8] = c1;
    __syncthreads();
#pragma unroll
    for (int kk = 0; kk < 64; kk += 32) {
      const int ko = kk + quad * 8;
      short8 a[2], b[4];
#pragma unroll
      for (int u = 0; u < 2; ++u) a[u] = *(const short8*)&As[(w * 32 + u * 16 + l16) * 64 + ko];
#pragma unroll
      for (int u = 0; u < 4; ++u) b[u] = *(const short8*)&Bs[(u * 16 + l16) * 64 + ko];
#pragma unroll
      for (int tm = 0; tm < 2; ++tm)
#pragma unroll
        for (int tn = 0; tn < 4; ++tn)
          acc[tm][tn] = __builtin_amdgcn_mfma_f32_16x16x32_bf16(a[tm], b[tn], acc[tm][tn], 0, 0, 0);
    }
    __syncthreads();
  }
  bf16* out = kv2 + (long)bh * 128 * 64;
#pragma unroll
  for (int tm = 0; tm < 2; ++tm)
#pragma unroll
    for (int tn = 0; tn < 4; ++tn) {
      const int d = tn * 16 + l16;
#pragma unroll
      for (int j = 0; j < 4; ++j) {
        const int ep = w * 32 + tm * 16 + quad * 4 + j;
        out[ep * 64 + d] = f2b(acc[tm][tn][j]);
      }
    }
}

// dinv[bh*2048+t] = 1 / max(sin_t*dot(qh, ks_sin) + cos_t*dot(qh, ks_cos), eps)
__global__ void den_kernel(const bf16* __restrict__ Qh, const float* __restrict__ ksum2,
                           float* __restrict__ dinv)
{
  __shared__ float ks[128];
  const int bh = blockIdx.y;
  const int t = blockIdx.x * 256 + threadIdx.x;
  if (threadIdx.x < 128) ks[threadIdx.x] = ksum2[bh * 128 + threadIdx.x];
  __syncthreads();
  const bf16* q = Qh + ((long)bh * 2048 + t) * 64;
  float d1 = 0.f, d2 = 0.f;
#pragma unroll
  for (int i = 0; i < 8; ++i) {
    short8 v = *(const short8*)&q[i * 8];
#pragma unroll
    for (int j = 0; j < 8; ++j) {
      const float f = s2f(v[j]);
      d1 += f * ks[i * 8 + j];
      d2 += f * ks[64 + i * 8 + j];
    }
  }
  const float ang = (float)(t + 1) * TRIG_C;
  const float den = __sinf(ang) * d1 + __cosf(ang) * d2;
  dinv[bh * 2048 + t] = 1.f / fmaxf(den, 1e-6f);
}

// att[(t*8+b)*1024 + h*64+e] = (sin_t*(Qh.kv2_sin^T) + cos_t*(Qh.kv2_cos^T)) * dinv
__global__ void attn_out(const bf16* __restrict__ Qh, const bf16* __restrict__ kv2,
                         const float* __restrict__ dinv, bf16* __restrict__ att)
{
  __shared__ __align__(16) bf16 Qs[128 * 64];
  __shared__ __align__(16) bf16 Ks[128 * 64];
  const int bh = blockIdx.y;
  const int t0 = blockIdx.x * 128;
  const int tid = threadIdx.x, w = tid >> 6, l = tid & 63;
  const int quad = l >> 4, l16 = l & 15;
  const int lrow = l >> 3, lcol = (l & 7) * 8;
  const bf16* Qg = Qh + ((long)bh * 2048 + t0) * 64;
  const bf16* Kg = kv2 + (long)bh * 128 * 64;
#pragma unroll
  for (int i = 0; i < 4; ++i) {
    const int c = w * 4 + i, r = c * 8 + lrow;
    GLL16(Qg + (long)r * 64 + lcol, &Qs[c * 512]);
  }
#pragma unroll
  for (int i = 0; i < 4; ++i) {
    const int c = w * 4 + i, r = c * 8 + lrow;
    GLL16(Kg + (long)r * 64 + lcol, &Ks[c * 512]);
  }
  __syncthreads();

  f32x4 accs[2][4] = {}, accc[2][4] = {};
#pragma unroll
  for (int kk = 0; kk < 64; kk += 32) {
    const int ko = kk + quad * 8;
    short8 a[2], bs[4], bc[4];
#pragma unroll
    for (int u = 0; u < 2; ++u) a[u] = *(const short8*)&Qs[(w * 32 + u * 16 + l16) * 64 + ko];
#pragma unroll
    for (int u = 0; u < 4; ++u) {
      bs[u] = *(const short8*)&Ks[(u * 16 + l16) * 64 + ko];
      bc[u] = *(const short8*)&Ks[(64 + u * 16 + l16) * 64 + ko];
    }
#pragma unroll
    for (int tm = 0; tm < 2; ++tm)
#pragma unroll
      for (int tn = 0; tn < 4; ++tn) {
        accs[tm][tn] = __builtin_amdgcn_mfma_f32_16x16x32_bf16(a[tm], bs[tn], accs[tm][tn], 0, 0, 0);
        accc[tm][tn] = __builtin_amdgcn_mfma_f32_16x16x32_bf16(a[tm], bc[tn], accc[tm][tn], 0, 0, 0);
      }
  }
  const int bb = bh >> 4, h = bh & 15;
#pragma unroll
  for (int tm = 0; tm < 2; ++tm)
#pragma unroll
    for (int j = 0; j < 4; ++j) {
      const int tr = w * 32 + tm * 16 + quad * 4 + j;
      const int t = t0 + tr;
      const float di = dinv[bh * 2048 + t];
      const float ang = (float)(t + 1) * TRIG_C;
      const float sn = __sinf(ang), cs = __cosf(ang);
#pragma unroll
      for (int tn = 0; tn < 4; ++tn) {
        const int e = tn * 16 + l16;
        const float v = (sn * accs[tm][tn][j] + cs * accc[tm][tn][j]) * di;
        att[((long)t * 8 + bb) * 1024 + h * 64 + e] = f2b(v);
      }
    }
}

extern "C" void kernel_launch(void* const* d_in, const int* in_sizes, int n_in,
                              void* d_out, int out_size, void* d_ws, size_t ws_size,
                              hipStream_t stream)
{
  const void* query  = d_in[0];
  const void* key_in = d_in[1];
  const void* value  = d_in[2];
  const void* wq = d_in[3];  const void* bq = d_in[4];
  const void* wk = d_in[5];  const void* bk = d_in[6];
  const void* wv = d_in[7];  const void* bv = d_in[8];
  const void* wo = d_in[9];  const void* bo = d_in[10];

  // ws layout (~36 MB): flag | ksum2 | kv2 | dinv | KhT(=ATT)
  char* ws = (char*)d_ws;
  int*   flag  = (int*)(ws);                   // 256 B
  float* ksum2 = (float*)(ws + 256);           // 64 KB
  bf16*  kv2   = (bf16*)(ws + 65792);          // 2 MB
  float* dinv  = (float*)(ws + 2162944);       // 1 MB
  bf16*  KhT   = (bf16*)(ws + 4194304);        // 32 MB; dead after kv_gemm
  bf16*  ATT   = KhT;                          // alias
  // d_out time-multiplexed (>=32 MB in both dtype cases): VhT -> Qh -> output
  bf16*  VhT   = (bf16*)d_out;
  bf16*  Qh    = (bf16*)d_out;

  dim3 blk(256);
  dim3 gproj(8, 128);
  hipLaunchKernelGGL(detect_dtype, dim3(1), dim3(64), 0, stream,
                     (const unsigned*)query, flag);
  hipLaunchKernelGGL((proj_gemm<1>), gproj, blk, 0, stream, key_in, wk, bk, KhT, flag);
  hipLaunchKernelGGL((proj_gemm<2>), gproj, blk, 0, stream, value,  wv, bv, VhT, flag);
  hipLaunchKernelGGL(ksum2_kernel, dim3(2048), blk, 0, stream, KhT, ksum2);
  hipLaunchKernelGGL(kv_gemm, dim3(128), blk, 0, stream, VhT, KhT, kv2);
  hipLaunchKernelGGL((proj_gemm<0>), gproj, blk, 0, stream, query, wq, bq, Qh, flag);
  hipLaunchKernelGGL(den_kernel, dim3(8, 128), blk, 0, stream, Qh, ksum2, dinv);
  hipLaunchKernelGGL(attn_out, dim3(16, 128), blk, 0, stream, Qh, kv2, dinv, ATT);
  hipLaunchKernelGGL((proj_gemm<3>), gproj, blk, 0, stream, ATT, wo, bo, d_out, flag);
}

// Round 5
// 578.334 us; speedup vs baseline: 1.3121x; 1.3121x over previous
//
#include <hip/hip_runtime.h>
#include <hip/hip_bf16.h>

using bf16 = __hip_bfloat16;
typedef __attribute__((ext_vector_type(8))) short short8;   // 8 bf16 = 4 VGPRs (MFMA A/B frag)
typedef __attribute__((ext_vector_type(4))) float f32x4;    // MFMA C/D frag

// async global->LDS, 16B per lane; LDS dest = wave-uniform base + lane*16
#define GLL16(gp, lp) __builtin_amdgcn_global_load_lds( \
    (__attribute__((address_space(1))) void*)(gp),      \
    (__attribute__((address_space(3))) void*)(lp), 16, 0, 0)

__device__ __forceinline__ bf16 f2b(float x) { return __float2bfloat16(x); }
__device__ __forceinline__ float s2f(short x) {
  unsigned u = ((unsigned)(unsigned short)x) << 16;
  return __uint_as_float(u);
}
__device__ __forceinline__ short f2s(float x) {
  bf16 h = __float2bfloat16(x);
  return *reinterpret_cast<short*>(&h);
}

#define TRIG_C (1.5707963268f / 2048.0f)   // (pi/2)/len, len = T = S = 2048

// ---------------------------------------------------------------------------
// f32 -> bf16 elementwise convert, 8 elems/thread (2x float4 in, 1x 16B out)
// ---------------------------------------------------------------------------
__global__ void cvt_f32_bf16(const float* __restrict__ src, bf16* __restrict__ dst, int n8)
{
  const int i = blockIdx.x * 256 + threadIdx.x;
  if (i >= n8) return;
  const f32x4 a = ((const f32x4*)src)[i * 2];
  const f32x4 b = ((const f32x4*)src)[i * 2 + 1];
  short8 o;
#pragma unroll
  for (int j = 0; j < 4; ++j) { o[j] = f2s(a[j]); o[4 + j] = f2s(b[j]); }
  *(short8*)&dst[i * 8] = o;
}

// ---------------------------------------------------------------------------
// NT GEMM (pure bf16, GLL16 staging): A (M=16384,K=1024) rm, W (N=1024,K=1024) rm.
// 128x128 tile, BK=64, 256 thr (4 waves), each wave 64x64 = 4x4 mfma tiles.
// MODE 0: q-proj -> Qh  (bh, 2048, 64) d-contig, relu(v*0.125)   [bf16 out]
// MODE 1: k-proj -> KhT (bh, 64, 2048) s-contig, relu(v)         [bf16 out]
// MODE 2: v-proj -> VhT (bh, 64, 2048) s-contig                  [bf16 out]
// MODE 3: o-proj -> out (16384, 1024)  row-major                 [f32 out]
// bias is f32 (harness input read directly).
// ---------------------------------------------------------------------------
template<int MODE>
__global__ void proj_gemm(const bf16* __restrict__ A, const bf16* __restrict__ W,
                          const float* __restrict__ bias, void* __restrict__ O)
{
  constexpr int K = 1024;
  constexpr int BK = 64;
  __shared__ __align__(16) bf16 As[128 * BK];
  __shared__ __align__(16) bf16 Bs[128 * BK];

  const int tid = threadIdx.x;
  const int w = tid >> 6, l = tid & 63;
  const int quad = l >> 4, l16 = l & 15;
  const int lrow = l >> 3, lcol = (l & 7) * 8;
  const long mblk = (long)blockIdx.y * 128;
  const int  nblk = blockIdx.x * 128;
  const int wr = (w >> 1) * 64, wc = (w & 1) * 64;

  const bf16* Ag = A + mblk * K;
  const bf16* Wg = W + (long)nblk * K;

  f32x4 acc[4][4] = {};

  for (int kt = 0; kt < K; kt += BK) {
#pragma unroll
    for (int i = 0; i < 4; ++i) {
      const int c = w * 4 + i;            // chunk: 8 rows x 64 cols = 1KB
      const int r = c * 8 + lrow;
      GLL16(Ag + (long)r * K + kt + lcol, &As[c * 512]);
      GLL16(Wg + (long)r * K + kt + lcol, &Bs[c * 512]);
    }
    __syncthreads();   // drains vmcnt -> LDS data landed
#pragma unroll
    for (int kk = 0; kk < BK; kk += 32) {
      const int ko = kk + quad * 8;
      short8 a[4], b[4];
#pragma unroll
      for (int u = 0; u < 4; ++u)
        a[u] = *(const short8*)&As[(wr + u * 16 + l16) * BK + ko];
#pragma unroll
      for (int u = 0; u < 4; ++u)
        b[u] = *(const short8*)&Bs[(wc + u * 16 + l16) * BK + ko];
#pragma unroll
      for (int tm = 0; tm < 4; ++tm)
#pragma unroll
        for (int tn = 0; tn < 4; ++tn)
          acc[tm][tn] = __builtin_amdgcn_mfma_f32_16x16x32_bf16(a[tm], b[tn], acc[tm][tn], 0, 0, 0);
    }
    __syncthreads();
  }

  // epilogue: C/D layout col=l&15, row=quad*4+reg
#pragma unroll
  for (int tm = 0; tm < 4; ++tm) {
    const int row0 = (int)mblk + wr + tm * 16 + quad * 4;
#pragma unroll
    for (int tn = 0; tn < 4; ++tn) {
      const int col = nblk + wc + tn * 16 + l16;
      const float bc = bias[col];
#pragma unroll
      for (int j = 0; j < 4; ++j) {
        const int row = row0 + j;
        float v = acc[tm][tn][j] + bc;
        if (MODE == 0) {
          const int t = row >> 3, bb = row & 7;           // row = t*8 + b
          const int h = col >> 6, d = col & 63;
          ((bf16*)O)[((long)(bb * 16 + h) * 2048 + t) * 64 + d] = f2b(fmaxf(v * 0.125f, 0.f));
        } else if (MODE == 1) {
          const int s = row >> 3, bb = row & 7;
          const int h = col >> 6, d = col & 63;
          ((bf16*)O)[((long)(bb * 16 + h) * 64 + d) * 2048 + s] = f2b(fmaxf(v, 0.f));
        } else if (MODE == 2) {
          const int s = row >> 3, bb = row & 7;
          const int h = col >> 6, e = col & 63;
          ((bf16*)O)[((long)(bb * 16 + h) * 64 + e) * 2048 + s] = f2b(v);
        } else {
          ((float*)O)[(long)row * 1024 + col] = v;
        }
      }
    }
  }
}

// ---------------------------------------------------------------------------
// ksum2[bh*128 + d]      = sum_s sin_s * KhT[bh][d][s]
// ksum2[bh*128 + 64 + d] = sum_s cos_s * KhT[bh][d][s]
// ---------------------------------------------------------------------------
__global__ void ksum2_kernel(const bf16* __restrict__ KhT, float* __restrict__ ksum2)
{
  const int gw = (blockIdx.x * 256 + threadIdx.x) >> 6;   // 0..8191
  const int l = threadIdx.x & 63;
  const int bh = gw >> 6, d = gw & 63;
  const bf16* row = KhT + ((long)bh * 64 + d) * 2048;
  float ss = 0.f, cc = 0.f;
#pragma unroll
  for (int i = 0; i < 4; ++i) {
    short8 v = *(const short8*)&row[i * 512 + l * 8];
#pragma unroll
    for (int j = 0; j < 8; ++j) {
      const int s = i * 512 + l * 8 + j;
      const float ang = (float)(s + 1) * TRIG_C;
      const float f = s2f(v[j]);
      ss += f * __sinf(ang);
      cc += f * __cosf(ang);
    }
  }
#pragma unroll
  for (int off = 32; off > 0; off >>= 1) {
    ss += __shfl_down(ss, off);
    cc += __shfl_down(cc, off);
  }
  if (l == 0) {
    ksum2[bh * 128 + d]      = ss;
    ksum2[bh * 128 + 64 + d] = cc;
  }
}

// ---------------------------------------------------------------------------
// kv2[bh][e'][d], e'<64: sum_s sin_s*v[s,e]*k[s,d]; e'>=64: cos version.
// M=128 (e'), N=64 (d), K=2048. One block per bh.
// ---------------------------------------------------------------------------
__global__ void kv_gemm(const bf16* __restrict__ VhT, const bf16* __restrict__ KhT,
                        bf16* __restrict__ kv2)
{
  __shared__ __align__(16) bf16 As[128 * 64];
  __shared__ __align__(16) bf16 Bs[64 * 64];
  const int bh = blockIdx.x;
  const int tid = threadIdx.x, w = tid >> 6, l = tid & 63;
  const int quad = l >> 4, l16 = l & 15;
  const int lrow = l >> 3, lcol = (l & 7) * 8;
  const bf16* Vg = VhT + (long)bh * 64 * 2048;
  const bf16* Kg = KhT + (long)bh * 64 * 2048;
  const int ar = tid >> 2, ac = (tid & 3) * 16;   // A-staging role

  f32x4 acc[2][4] = {};

  for (int kt = 0; kt < 2048; kt += 64) {
#pragma unroll
    for (int i = 0; i < 2; ++i) {                 // Bs: KhT rows d=0..63
      const int c = w * 2 + i, r = c * 8 + lrow;
      GLL16(Kg + (long)r * 2048 + kt + lcol, &Bs[c * 512]);
    }
    // As: load V tile 64x64, scale by sin/cos, write expanded 128x64
    short8 v0 = *(const short8*)&Vg[(long)ar * 2048 + kt + ac];
    short8 v1 = *(const short8*)&Vg[(long)ar * 2048 + kt + ac + 8];
    short8 s0, s1, c0, c1;
#pragma unroll
    for (int j = 0; j < 8; ++j) {
      const int sA = kt + ac + j, sB = sA + 8;
      const float angA = (float)(sA + 1) * TRIG_C, angB = (float)(sB + 1) * TRIG_C;
      const float fA = s2f(v0[j]), fB = s2f(v1[j]);
      s0[j] = f2s(fA * __sinf(angA)); c0[j] = f2s(fA * __cosf(angA));
      s1[j] = f2s(fB * __sinf(angB)); c1[j] = f2s(fB * __cosf(angB));
    }
    *(short8*)&As[ar * 64 + ac]            = s0;
    *(short8*)&As[ar * 64 + ac + 8]        = s1;
    *(short8*)&As[(ar + 64) * 64 + ac]     = c0;
    *(short8*)&As[(ar + 64) * 64 + ac + 8] = c1;
    __syncthreads();
#pragma unroll
    for (int kk = 0; kk < 64; kk += 32) {
      const int ko = kk + quad * 8;
      short8 a[2], b[4];
#pragma unroll
      for (int u = 0; u < 2; ++u) a[u] = *(const short8*)&As[(w * 32 + u * 16 + l16) * 64 + ko];
#pragma unroll
      for (int u = 0; u < 4; ++u) b[u] = *(const short8*)&Bs[(u * 16 + l16) * 64 + ko];
#pragma unroll
      for (int tm = 0; tm < 2; ++tm)
#pragma unroll
        for (int tn = 0; tn < 4; ++tn)
          acc[tm][tn] = __builtin_amdgcn_mfma_f32_16x16x32_bf16(a[tm], b[tn], acc[tm][tn], 0, 0, 0);
    }
    __syncthreads();
  }
  bf16* out = kv2 + (long)bh * 128 * 64;
#pragma unroll
  for (int tm = 0; tm < 2; ++tm)
#pragma unroll
    for (int tn = 0; tn < 4; ++tn) {
      const int d = tn * 16 + l16;
#pragma unroll
      for (int j = 0; j < 4; ++j) {
        const int ep = w * 32 + tm * 16 + quad * 4 + j;
        out[ep * 64 + d] = f2b(acc[tm][tn][j]);
      }
    }
}

// dinv[bh*2048+t] = 1 / max(sin_t*dot(qh, ks_sin) + cos_t*dot(qh, ks_cos), eps)
__global__ void den_kernel(const bf16* __restrict__ Qh, const float* __restrict__ ksum2,
                           float* __restrict__ dinv)
{
  __shared__ float ks[128];
  const int bh = blockIdx.y;
  const int t = blockIdx.x * 256 + threadIdx.x;
  if (threadIdx.x < 128) ks[threadIdx.x] = ksum2[bh * 128 + threadIdx.x];
  __syncthreads();
  const bf16* q = Qh + ((long)bh * 2048 + t) * 64;
  float d1 = 0.f, d2 = 0.f;
#pragma unroll
  for (int i = 0; i < 8; ++i) {
    short8 v = *(const short8*)&q[i * 8];
#pragma unroll
    for (int j = 0; j < 8; ++j) {
      const float f = s2f(v[j]);
      d1 += f * ks[i * 8 + j];
      d2 += f * ks[64 + i * 8 + j];
    }
  }
  const float ang = (float)(t + 1) * TRIG_C;
  const float den = __sinf(ang) * d1 + __cosf(ang) * d2;
  dinv[bh * 2048 + t] = 1.f / fmaxf(den, 1e-6f);
}

// att[(t*8+b)*1024 + h*64+e] = (sin_t*(Qh.kv2_sin^T) + cos_t*(Qh.kv2_cos^T)) * dinv
__global__ void attn_out(const bf16* __restrict__ Qh, const bf16* __restrict__ kv2,
                         const float* __restrict__ dinv, bf16* __restrict__ att)
{
  __shared__ __align__(16) bf16 Qs[128 * 64];
  __shared__ __align__(16) bf16 Ks[128 * 64];
  const int bh = blockIdx.y;
  const int t0 = blockIdx.x * 128;
  const int tid = threadIdx.x, w = tid >> 6, l = tid & 63;
  const int quad = l >> 4, l16 = l & 15;
  const int lrow = l >> 3, lcol = (l & 7) * 8;
  const bf16* Qg = Qh + ((long)bh * 2048 + t0) * 64;
  const bf16* Kg = kv2 + (long)bh * 128 * 64;
#pragma unroll
  for (int i = 0; i < 4; ++i) {
    const int c = w * 4 + i, r = c * 8 + lrow;
    GLL16(Qg + (long)r * 64 + lcol, &Qs[c * 512]);
  }
#pragma unroll
  for (int i = 0; i < 4; ++i) {
    const int c = w * 4 + i, r = c * 8 + lrow;
    GLL16(Kg + (long)r * 64 + lcol, &Ks[c * 512]);
  }
  __syncthreads();

  f32x4 accs[2][4] = {}, accc[2][4] = {};
#pragma unroll
  for (int kk = 0; kk < 64; kk += 32) {
    const int ko = kk + quad * 8;
    short8 a[2], bs[4], bc[4];
#pragma unroll
    for (int u = 0; u < 2; ++u) a[u] = *(const short8*)&Qs[(w * 32 + u * 16 + l16) * 64 + ko];
#pragma unroll
    for (int u = 0; u < 4; ++u) {
      bs[u] = *(const short8*)&Ks[(u * 16 + l16) * 64 + ko];
      bc[u] = *(const short8*)&Ks[(64 + u * 16 + l16) * 64 + ko];
    }
#pragma unroll
    for (int tm = 0; tm < 2; ++tm)
#pragma unroll
      for (int tn = 0; tn < 4; ++tn) {
        accs[tm][tn] = __builtin_amdgcn_mfma_f32_16x16x32_bf16(a[tm], bs[tn], accs[tm][tn], 0, 0, 0);
        accc[tm][tn] = __builtin_amdgcn_mfma_f32_16x16x32_bf16(a[tm], bc[tn], accc[tm][tn], 0, 0, 0);
      }
  }
  const int bb = bh >> 4, h = bh & 15;
#pragma unroll
  for (int tm = 0; tm < 2; ++tm)
#pragma unroll
    for (int j = 0; j < 4; ++j) {
      const int tr = w * 32 + tm * 16 + quad * 4 + j;
      const int t = t0 + tr;
      const float di = dinv[bh * 2048 + t];
      const float ang = (float)(t + 1) * TRIG_C;
      const float sn = __sinf(ang), cs = __cosf(ang);
#pragma unroll
      for (int tn = 0; tn < 4; ++tn) {
        const int e = tn * 16 + l16;
        const float v = (sn * accs[tm][tn][j] + cs * accc[tm][tn][j]) * di;
        att[((long)t * 8 + bb) * 1024 + h * 64 + e] = f2b(v);
      }
    }
}

extern "C" void kernel_launch(void* const* d_in, const int* in_sizes, int n_in,
                              void* d_out, int out_size, void* d_ws, size_t ws_size,
                              hipStream_t stream)
{
  const float* query  = (const float*)d_in[0];
  const float* key_in = (const float*)d_in[1];
  const float* value  = (const float*)d_in[2];
  const float* wq = (const float*)d_in[3];  const float* bq = (const float*)d_in[4];
  const float* wk = (const float*)d_in[5];  const float* bk = (const float*)d_in[6];
  const float* wv = (const float*)d_in[7];  const float* bv = (const float*)d_in[8];
  const float* wo = (const float*)d_in[9];  const float* bo = (const float*)d_in[10];

  // ws layout (37.06 MB total, within the proven >=37.75 MB):
  char* ws = (char*)d_ws;
  float* ksum2 = (float*)(ws);                 // 64 KB
  float* dinv  = (float*)(ws + 65536);         // 1 MB
  bf16*  kv2   = (bf16*)(ws + 1114112);        // 2 MB
  bf16*  Wslot = (bf16*)(ws + 3211264);        // 2 MB (Wk -> Wv -> Wq -> Wo)
  bf16*  R1    = (bf16*)(ws + 5308416);        // 32 MB (KhT -> ATT)
  bf16*  KhT = R1, *ATT = R1;
  // d_out (64 MB f32) time-multiplexed as two 32 MB bf16 regions:
  bf16*  D1 = (bf16*)d_out;                    // Kbf -> VhT -> Qh
  bf16*  D2 = (bf16*)d_out + 16777216;         // Vbf -> Qbf
  // final proj_gemm<3> writes f32 over D1+D2 (both dead by then)

  dim3 blk(256);
  dim3 gproj(8, 128);
  const int nBig = 16777216 / 8, gBig = nBig / 256;   // inputs: 8192 blocks
  const int nW   = 1048576 / 8,  gW   = nW / 256;     // weights: 512 blocks

  // K path
  hipLaunchKernelGGL(cvt_f32_bf16, dim3(gBig), blk, 0, stream, key_in, D1, nBig);
  hipLaunchKernelGGL(cvt_f32_bf16, dim3(gW),   blk, 0, stream, wk, Wslot, nW);
  hipLaunchKernelGGL((proj_gemm<1>), gproj, blk, 0, stream, D1, Wslot, bk, KhT);
  hipLaunchKernelGGL(ksum2_kernel, dim3(2048), blk, 0, stream, KhT, ksum2);
  // V path
  hipLaunchKernelGGL(cvt_f32_bf16, dim3(gBig), blk, 0, stream, value, D2, nBig);
  hipLaunchKernelGGL(cvt_f32_bf16, dim3(gW),   blk, 0, stream, wv, Wslot, nW);
  hipLaunchKernelGGL((proj_gemm<2>), gproj, blk, 0, stream, D2, Wslot, bv, D1); // VhT=D1
  hipLaunchKernelGGL(kv_gemm, dim3(128), blk, 0, stream, D1, KhT, kv2);
  // Q path
  hipLaunchKernelGGL(cvt_f32_bf16, dim3(gBig), blk, 0, stream, query, D2, nBig);
  hipLaunchKernelGGL(cvt_f32_bf16, dim3(gW),   blk, 0, stream, wq, Wslot, nW);
  hipLaunchKernelGGL((proj_gemm<0>), gproj, blk, 0, stream, D2, Wslot, bq, D1); // Qh=D1
  hipLaunchKernelGGL(den_kernel, dim3(8, 128), blk, 0, stream, D1, ksum2, dinv);
  hipLaunchKernelGGL(attn_out, dim3(16, 128), blk, 0, stream, D1, kv2, dinv, ATT);
  // O path
  hipLaunchKernelGGL(cvt_f32_bf16, dim3(gW),   blk, 0, stream, wo, Wslot, nW);
  hipLaunchKernelGGL((proj_gemm<3>), gproj, blk, 0, stream, ATT, Wslot, bo, d_out);
}

// Round 6
// 570.670 us; speedup vs baseline: 1.3297x; 1.0134x over previous
//
#include <hip/hip_runtime.h>
#include <hip/hip_bf16.h>

using bf16 = __hip_bfloat16;
typedef __attribute__((ext_vector_type(8))) short short8;   // 8 bf16 = 4 VGPRs (MFMA A/B frag)
typedef __attribute__((ext_vector_type(4))) float f32x4;    // MFMA C/D frag

// async global->LDS, 16B per lane; LDS dest = wave-uniform base + lane*16
#define GLL16(gp, lp) __builtin_amdgcn_global_load_lds( \
    (__attribute__((address_space(1))) void*)(gp),      \
    (__attribute__((address_space(3))) void*)(lp), 16, 0, 0)

__device__ __forceinline__ bf16 f2b(float x) { return __float2bfloat16(x); }
__device__ __forceinline__ float s2f(short x) {
  unsigned u = ((unsigned)(unsigned short)x) << 16;
  return __uint_as_float(u);
}
__device__ __forceinline__ short f2s(float x) {
  bf16 h = __float2bfloat16(x);
  return *reinterpret_cast<short*>(&h);
}

#define TRIG_C (1.5707963268f / 2048.0f)   // (pi/2)/len, len = T = S = 2048

// ---------------------------------------------------------------------------
// f32 -> bf16 elementwise convert, 8 elems/thread (2x float4 in, 1x 16B out)
// ---------------------------------------------------------------------------
__global__ void cvt_f32_bf16(const float* __restrict__ src, bf16* __restrict__ dst, int n8)
{
  const int i = blockIdx.x * 256 + threadIdx.x;
  if (i >= n8) return;
  const f32x4 a = ((const f32x4*)src)[i * 2];
  const f32x4 b = ((const f32x4*)src)[i * 2 + 1];
  short8 o;
#pragma unroll
  for (int j = 0; j < 4; ++j) { o[j] = f2s(a[j]); o[4 + j] = f2s(b[j]); }
  *(short8*)&dst[i * 8] = o;
}

// ---------------------------------------------------------------------------
// NT GEMM (pure bf16, GLL16 staging): A (M=16384,K=1024) rm, W (N=1024,K=1024) rm.
// 128x128 tile, BK=64, 256 thr (4 waves), each wave 64x64 = 4x4 mfma tiles.
// 1D grid of 1024 blocks, XCD-aware swizzle: xcd = id&7 = m%8, n fastest
// within an XCD so each A m-panel stays resident in that XCD's L2.
// MODE 0: q-proj -> Qh  (bh, 2048, 64) d-contig, relu(v*0.125)   [bf16 out]
// MODE 1: k-proj -> KhT (bh, 64, 2048) s-contig, relu(v)         [bf16 out]
// MODE 2: v-proj -> VhT (bh, 64, 2048) s-contig                  [bf16 out]
// MODE 3: o-proj -> out (16384, 1024)  row-major                 [f32 out]
// ---------------------------------------------------------------------------
template<int MODE>
__global__ void proj_gemm(const bf16* __restrict__ A, const bf16* __restrict__ W,
                          const float* __restrict__ bias, void* __restrict__ O)
{
  constexpr int K = 1024;
  constexpr int BK = 64;
  __shared__ __align__(16) bf16 As[128 * BK];
  __shared__ __align__(16) bf16 Bs[128 * BK];

  const int tid = threadIdx.x;
  const int w = tid >> 6, l = tid & 63;
  const int quad = l >> 4, l16 = l & 15;
  const int lrow = l >> 3, lcol = (l & 7) * 8;

  // swizzle: bid = xcd + 8*(ni + 8*mi_hi); m = xcd + 8*mi_hi (fixed m%8 per XCD)
  const int bid = blockIdx.x;
  const int mi = (bid & 7) + 8 * (bid >> 6);       // 0..127
  const int ni = (bid >> 3) & 7;                   // 0..7
  const long mblk = (long)mi * 128;
  const int  nblk = ni * 128;
  const int wr = (w >> 1) * 64, wc = (w & 1) * 64;

  const bf16* Ag = A + mblk * K;
  const bf16* Wg = W + (long)nblk * K;

  f32x4 acc[4][4] = {};

  for (int kt = 0; kt < K; kt += BK) {
#pragma unroll
    for (int i = 0; i < 4; ++i) {
      const int c = w * 4 + i;            // chunk: 8 rows x 64 cols = 1KB
      const int r = c * 8 + lrow;
      GLL16(Ag + (long)r * K + kt + lcol, &As[c * 512]);
      GLL16(Wg + (long)r * K + kt + lcol, &Bs[c * 512]);
    }
    __syncthreads();   // drains vmcnt -> LDS data landed
#pragma unroll
    for (int kk = 0; kk < BK; kk += 32) {
      const int ko = kk + quad * 8;
      short8 a[4], b[4];
#pragma unroll
      for (int u = 0; u < 4; ++u)
        a[u] = *(const short8*)&As[(wr + u * 16 + l16) * BK + ko];
#pragma unroll
      for (int u = 0; u < 4; ++u)
        b[u] = *(const short8*)&Bs[(wc + u * 16 + l16) * BK + ko];
#pragma unroll
      for (int tm = 0; tm < 4; ++tm)
#pragma unroll
        for (int tn = 0; tn < 4; ++tn)
          acc[tm][tn] = __builtin_amdgcn_mfma_f32_16x16x32_bf16(a[tm], b[tn], acc[tm][tn], 0, 0, 0);
    }
    __syncthreads();
  }

  // epilogue: C/D layout col=l&15, row=quad*4+reg
#pragma unroll
  for (int tm = 0; tm < 4; ++tm) {
    const int row0 = (int)mblk + wr + tm * 16 + quad * 4;
#pragma unroll
    for (int tn = 0; tn < 4; ++tn) {
      const int col = nblk + wc + tn * 16 + l16;
      const float bc = bias[col];
#pragma unroll
      for (int j = 0; j < 4; ++j) {
        const int row = row0 + j;
        float v = acc[tm][tn][j] + bc;
        if (MODE == 0) {
          const int t = row >> 3, bb = row & 7;           // row = t*8 + b
          const int h = col >> 6, d = col & 63;
          ((bf16*)O)[((long)(bb * 16 + h) * 2048 + t) * 64 + d] = f2b(fmaxf(v * 0.125f, 0.f));
        } else if (MODE == 1) {
          const int s = row >> 3, bb = row & 7;
          const int h = col >> 6, d = col & 63;
          ((bf16*)O)[((long)(bb * 16 + h) * 64 + d) * 2048 + s] = f2b(fmaxf(v, 0.f));
        } else if (MODE == 2) {
          const int s = row >> 3, bb = row & 7;
          const int h = col >> 6, e = col & 63;
          ((bf16*)O)[((long)(bb * 16 + h) * 64 + e) * 2048 + s] = f2b(v);
        } else {
          ((float*)O)[(long)row * 1024 + col] = v;
        }
      }
    }
  }
}

// ---------------------------------------------------------------------------
// ksum2[bh*128 + d]      = sum_s sin_s * KhT[bh][d][s]
// ksum2[bh*128 + 64 + d] = sum_s cos_s * KhT[bh][d][s]
// ---------------------------------------------------------------------------
__global__ void ksum2_kernel(const bf16* __restrict__ KhT, float* __restrict__ ksum2)
{
  const int gw = (blockIdx.x * 256 + threadIdx.x) >> 6;   // 0..8191
  const int l = threadIdx.x & 63;
  const int bh = gw >> 6, d = gw & 63;
  const bf16* row = KhT + ((long)bh * 64 + d) * 2048;
  float ss = 0.f, cc = 0.f;
#pragma unroll
  for (int i = 0; i < 4; ++i) {
    short8 v = *(const short8*)&row[i * 512 + l * 8];
#pragma unroll
    for (int j = 0; j < 8; ++j) {
      const int s = i * 512 + l * 8 + j;
      const float ang = (float)(s + 1) * TRIG_C;
      const float f = s2f(v[j]);
      ss += f * __sinf(ang);
      cc += f * __cosf(ang);
    }
  }
#pragma unroll
  for (int off = 32; off > 0; off >>= 1) {
    ss += __shfl_down(ss, off);
    cc += __shfl_down(cc, off);
  }
  if (l == 0) {
    ksum2[bh * 128 + d]      = ss;
    ksum2[bh * 128 + 64 + d] = cc;
  }
}

// ---------------------------------------------------------------------------
// kv2[bh][f*64+e][d] = sum_s trig_f(s)*v[s,e]*k[s,d],  f=blockIdx.y (0=sin,1=cos)
// Per block: M=64 (e), N=64 (d), K=2048. Grid (128, 2).
// ---------------------------------------------------------------------------
__global__ void kv_gemm(const bf16* __restrict__ VhT, const bf16* __restrict__ KhT,
                        bf16* __restrict__ kv2)
{
  __shared__ __align__(16) bf16 As[64 * 64];
  __shared__ __align__(16) bf16 Bs[64 * 64];
  const int bh = blockIdx.x;
  const int fl = blockIdx.y;                       // 0=sin, 1=cos
  const int tid = threadIdx.x, w = tid >> 6, l = tid & 63;
  const int quad = l >> 4, l16 = l & 15;
  const int lrow = l >> 3, lcol = (l & 7) * 8;
  const bf16* Vg = VhT + (long)bh * 64 * 2048;
  const bf16* Kg = KhT + (long)bh * 64 * 2048;
  const int ar = tid >> 2, ac = (tid & 3) * 16;    // A-staging role

  f32x4 acc[4] = {};

  for (int kt = 0; kt < 2048; kt += 64) {
#pragma unroll
    for (int i = 0; i < 2; ++i) {                  // Bs: KhT rows d=0..63
      const int c = w * 2 + i, r = c * 8 + lrow;
      GLL16(Kg + (long)r * 2048 + kt + lcol, &Bs[c * 512]);
    }
    // As: load V tile 64x64, scale by this block's trig flavor
    short8 v0 = *(const short8*)&Vg[(long)ar * 2048 + kt + ac];
    short8 v1 = *(const short8*)&Vg[(long)ar * 2048 + kt + ac + 8];
    short8 o0, o1;
#pragma unroll
    for (int j = 0; j < 8; ++j) {
      const int sA = kt + ac + j, sB = sA + 8;
      const float angA = (float)(sA + 1) * TRIG_C, angB = (float)(sB + 1) * TRIG_C;
      const float wA = fl ? __cosf(angA) : __sinf(angA);
      const float wB = fl ? __cosf(angB) : __sinf(angB);
      o0[j] = f2s(s2f(v0[j]) * wA);
      o1[j] = f2s(s2f(v1[j]) * wB);
    }
    *(short8*)&As[ar * 64 + ac]     = o0;
    *(short8*)&As[ar * 64 + ac + 8] = o1;
    __syncthreads();
#pragma unroll
    for (int kk = 0; kk < 64; kk += 32) {
      const int ko = kk + quad * 8;
      short8 a = *(const short8*)&As[(w * 16 + l16) * 64 + ko];
      short8 b[4];
#pragma unroll
      for (int u = 0; u < 4; ++u) b[u] = *(const short8*)&Bs[(u * 16 + l16) * 64 + ko];
#pragma unroll
      for (int tn = 0; tn < 4; ++tn)
        acc[tn] = __builtin_amdgcn_mfma_f32_16x16x32_bf16(a, b[tn], acc[tn], 0, 0, 0);
    }
    __syncthreads();
  }
  bf16* out = kv2 + (long)bh * 128 * 64 + fl * 64 * 64;
#pragma unroll
  for (int tn = 0; tn < 4; ++tn) {
    const int d = tn * 16 + l16;
#pragma unroll
    for (int j = 0; j < 4; ++j) {
      const int e = w * 16 + quad * 4 + j;
      out[e * 64 + d] = f2b(acc[tn][j]);
    }
  }
}

// dinv[bh*2048+t] = 1 / max(sin_t*dot(qh, ks_sin) + cos_t*dot(qh, ks_cos), eps)
__global__ void den_kernel(const bf16* __restrict__ Qh, const float* __restrict__ ksum2,
                           float* __restrict__ dinv)
{
  __shared__ float ks[128];
  const int bh = blockIdx.y;
  const int t = blockIdx.x * 256 + threadIdx.x;
  if (threadIdx.x < 128) ks[threadIdx.x] = ksum2[bh * 128 + threadIdx.x];
  __syncthreads();
  const bf16* q = Qh + ((long)bh * 2048 + t) * 64;
  float d1 = 0.f, d2 = 0.f;
#pragma unroll
  for (int i = 0; i < 8; ++i) {
    short8 v = *(const short8*)&q[i * 8];
#pragma unroll
    for (int j = 0; j < 8; ++j) {
      const float f = s2f(v[j]);
      d1 += f * ks[i * 8 + j];
      d2 += f * ks[64 + i * 8 + j];
    }
  }
  const float ang = (float)(t + 1) * TRIG_C;
  const float den = __sinf(ang) * d1 + __cosf(ang) * d2;
  dinv[bh * 2048 + t] = 1.f / fmaxf(den, 1e-6f);
}

// att[(t*8+b)*1024 + h*64+e] = (sin_t*(Qh.kv2_sin^T) + cos_t*(Qh.kv2_cos^T)) * dinv
__global__ void attn_out(const bf16* __restrict__ Qh, const bf16* __restrict__ kv2,
                         const float* __restrict__ dinv, bf16* __restrict__ att)
{
  __shared__ __align__(16) bf16 Qs[128 * 64];
  __shared__ __align__(16) bf16 Ks[128 * 64];
  const int bh = blockIdx.y;
  const int t0 = blockIdx.x * 128;
  const int tid = threadIdx.x, w = tid >> 6, l = tid & 63;
  const int quad = l >> 4, l16 = l & 15;
  const int lrow = l >> 3, lcol = (l & 7) * 8;
  const bf16* Qg = Qh + ((long)bh * 2048 + t0) * 64;
  const bf16* Kg = kv2 + (long)bh * 128 * 64;
#pragma unroll
  for (int i = 0; i < 4; ++i) {
    const int c = w * 4 + i, r = c * 8 + lrow;
    GLL16(Qg + (long)r * 64 + lcol, &Qs[c * 512]);
  }
#pragma unroll
  for (int i = 0; i < 4; ++i) {
    const int c = w * 4 + i, r = c * 8 + lrow;
    GLL16(Kg + (long)r * 64 + lcol, &Ks[c * 512]);
  }
  __syncthreads();

  f32x4 accs[2][4] = {}, accc[2][4] = {};
#pragma unroll
  for (int kk = 0; kk < 64; kk += 32) {
    const int ko = kk + quad * 8;
    short8 a[2], bs[4], bc[4];
#pragma unroll
    for (int u = 0; u < 2; ++u) a[u] = *(const short8*)&Qs[(w * 32 + u * 16 + l16) * 64 + ko];
#pragma unroll
    for (int u = 0; u < 4; ++u) {
      bs[u] = *(const short8*)&Ks[(u * 16 + l16) * 64 + ko];
      bc[u] = *(const short8*)&Ks[(64 + u * 16 + l16) * 64 + ko];
    }
#pragma unroll
    for (int tm = 0; tm < 2; ++tm)
#pragma unroll
      for (int tn = 0; tn < 4; ++tn) {
        accs[tm][tn] = __builtin_amdgcn_mfma_f32_16x16x32_bf16(a[tm], bs[tn], accs[tm][tn], 0, 0, 0);
        accc[tm][tn] = __builtin_amdgcn_mfma_f32_16x16x32_bf16(a[tm], bc[tn], accc[tm][tn], 0, 0, 0);
      }
  }
  const int bb = bh >> 4, h = bh & 15;
#pragma unroll
  for (int tm = 0; tm < 2; ++tm)
#pragma unroll
    for (int j = 0; j < 4; ++j) {
      const int tr = w * 32 + tm * 16 + quad * 4 + j;
      const int t = t0 + tr;
      const float di = dinv[bh * 2048 + t];
      const float ang = (float)(t + 1) * TRIG_C;
      const float sn = __sinf(ang), cs = __cosf(ang);
#pragma unroll
      for (int tn = 0; tn < 4; ++tn) {
        const int e = tn * 16 + l16;
        const float v = (sn * accs[tm][tn][j] + cs * accc[tm][tn][j]) * di;
        att[((long)t * 8 + bb) * 1024 + h * 64 + e] = f2b(v);
      }
    }
}

extern "C" void kernel_launch(void* const* d_in, const int* in_sizes, int n_in,
                              void* d_out, int out_size, void* d_ws, size_t ws_size,
                              hipStream_t stream)
{
  const float* query  = (const float*)d_in[0];
  const float* key_in = (const float*)d_in[1];
  const float* value  = (const float*)d_in[2];
  const float* wq = (const float*)d_in[3];  const float* bq = (const float*)d_in[4];
  const float* wk = (const float*)d_in[5];  const float* bk = (const float*)d_in[6];
  const float* wv = (const float*)d_in[7];  const float* bv = (const float*)d_in[8];
  const float* wo = (const float*)d_in[9];  const float* bo = (const float*)d_in[10];

  // ws layout (37.06 MB total, within the proven available size):
  char* ws = (char*)d_ws;
  float* ksum2 = (float*)(ws);                 // 64 KB
  float* dinv  = (float*)(ws + 65536);         // 1 MB
  bf16*  kv2   = (bf16*)(ws + 1114112);        // 2 MB
  bf16*  Wslot = (bf16*)(ws + 3211264);        // 2 MB (Wk -> Wv -> Wq -> Wo)
  bf16*  R1    = (bf16*)(ws + 5308416);        // 32 MB (KhT -> ATT)
  bf16*  KhT = R1, *ATT = R1;
  // d_out (64 MB f32) time-multiplexed as two 32 MB bf16 regions:
  bf16*  D1 = (bf16*)d_out;                    // Kbf -> VhT -> Qh
  bf16*  D2 = (bf16*)d_out + 16777216;         // Vbf -> Qbf
  // final proj_gemm<3> writes f32 over D1+D2 (both dead by then)

  dim3 blk(256);
  dim3 gproj(1024);
  const int nBig = 16777216 / 8, gBig = nBig / 256;   // inputs: 8192 blocks
  const int nW   = 1048576 / 8,  gW   = nW / 256;     // weights: 512 blocks

  // K path
  hipLaunchKernelGGL(cvt_f32_bf16, dim3(gBig), blk, 0, stream, key_in, D1, nBig);
  hipLaunchKernelGGL(cvt_f32_bf16, dim3(gW),   blk, 0, stream, wk, Wslot, nW);
  hipLaunchKernelGGL((proj_gemm<1>), gproj, blk, 0, stream, D1, Wslot, bk, KhT);
  hipLaunchKernelGGL(ksum2_kernel, dim3(2048), blk, 0, stream, KhT, ksum2);
  // V path
  hipLaunchKernelGGL(cvt_f32_bf16, dim3(gBig), blk, 0, stream, value, D2, nBig);
  hipLaunchKernelGGL(cvt_f32_bf16, dim3(gW),   blk, 0, stream, wv, Wslot, nW);
  hipLaunchKernelGGL((proj_gemm<2>), gproj, blk, 0, stream, D2, Wslot, bv, D1); // VhT=D1
  hipLaunchKernelGGL(kv_gemm, dim3(128, 2), blk, 0, stream, D1, KhT, kv2);
  // Q path
  hipLaunchKernelGGL(cvt_f32_bf16, dim3(gBig), blk, 0, stream, query, D2, nBig);
  hipLaunchKernelGGL(cvt_f32_bf16, dim3(gW),   blk, 0, stream, wq, Wslot, nW);
  hipLaunchKernelGGL((proj_gemm<0>), gproj, blk, 0, stream, D2, Wslot, bq, D1); // Qh=D1
  hipLaunchKernelGGL(den_kernel, dim3(8, 128), blk, 0, stream, D1, ksum2, dinv);
  hipLaunchKernelGGL(attn_out, dim3(16, 128), blk, 0, stream, D1, kv2, dinv, ATT);
  // O path
  hipLaunchKernelGGL(cvt_f32_bf16, dim3(gW),   blk, 0, stream, wo, Wslot, nW);
  hipLaunchKernelGGL((proj_gemm<3>), gproj, blk, 0, stream, ATT, Wslot, bo, d_out);
}